// Round 5
// baseline (409.363 us; speedup 1.0000x reference)
//
#include <hip/hip_runtime.h>

#define HID 128
#define NG 512
#define NC 10
#define SCHUNK 512

typedef unsigned int u32;
typedef unsigned short u16;
typedef __attribute__((ext_vector_type(8))) short short8;
typedef __attribute__((ext_vector_type(4))) float f32x4;

static __device__ __forceinline__ int gtid() {
    return blockIdx.x * blockDim.x + threadIdx.x;
}

// bf16 helpers (RNE pack, exact unpack)
static __device__ __forceinline__ u16 f2bf(float f) {
    u32 u = __float_as_uint(f);
    u32 r = u + 0x7fffu + ((u >> 16) & 1u);
    return (u16)(r >> 16);
}
static __device__ __forceinline__ float bf2f(u32 s) {
    return __uint_as_float(s << 16);
}
static __device__ __forceinline__ void bf8_unpack(uint4 u, float* f) {
    f[0] = bf2f(u.x & 0xffffu); f[1] = bf2f(u.x >> 16);
    f[2] = bf2f(u.y & 0xffffu); f[3] = bf2f(u.y >> 16);
    f[4] = bf2f(u.z & 0xffffu); f[5] = bf2f(u.z >> 16);
    f[6] = bf2f(u.w & 0xffffu); f[7] = bf2f(u.w >> 16);
}

// ---------- CSR build ----------

__global__ void k_hist(const int* __restrict__ dst, int* __restrict__ cnt, int E) {
    int i = gtid();
    if (i < E) atomicAdd(&cnt[dst[i]], 1);
}

__global__ __launch_bounds__(256) void k_scan1(const int* __restrict__ cnt,
                                               int* __restrict__ partial, int N) {
    __shared__ int s[256];
    int t = threadIdx.x;
    int i0 = blockIdx.x * SCHUNK + t * 2;
    int v = 0;
    if (i0 < N) v += cnt[i0];
    if (i0 + 1 < N) v += cnt[i0 + 1];
    s[t] = v;
    __syncthreads();
    for (int off = 128; off > 0; off >>= 1) {
        if (t < off) s[t] += s[t + off];
        __syncthreads();
    }
    if (t == 0) partial[blockIdx.x] = s[0];
}

__global__ __launch_bounds__(256) void k_scan2(int* __restrict__ partial, int B) {
    __shared__ int s[256];
    int t = threadIdx.x;
    int own = (t < B) ? partial[t] : 0;
    s[t] = own;
    __syncthreads();
    for (int off = 1; off < 256; off <<= 1) {
        int v = (t >= off) ? s[t - off] : 0;
        __syncthreads();
        s[t] += v;
        __syncthreads();
    }
    if (t < B) partial[t] = s[t] - own;  // exclusive
}

__global__ __launch_bounds__(256) void k_scan3(const int* __restrict__ cnt,
                                               const int* __restrict__ partial,
                                               int* __restrict__ rowptr,
                                               float* __restrict__ dinv, int N) {
    __shared__ int s[256];
    int t = threadIdx.x;
    int i0 = blockIdx.x * SCHUNK + t * 2;
    int c0 = 0, c1 = 0;
    if (i0 < N) c0 = cnt[i0];
    if (i0 + 1 < N) c1 = cnt[i0 + 1];
    int own = c0 + c1;
    s[t] = own;
    __syncthreads();
    for (int off = 1; off < 256; off <<= 1) {
        int v = (t >= off) ? s[t - off] : 0;
        __syncthreads();
        s[t] += v;
        __syncthreads();
    }
    int base = partial[blockIdx.x] + s[t] - own;
    if (i0 < N) { rowptr[i0] = base; dinv[i0] = rsqrtf(1.0f + (float)c0); }
    if (i0 + 1 < N) { rowptr[i0 + 1] = base + c0; dinv[i0 + 1] = rsqrtf(1.0f + (float)c1); }
    if (i0 >= N - 2 && i0 < N) rowptr[N] = base + own;
}

// scatter edges into CSR slots: packed[pos] = src only (norm recomputed from dinv)
__global__ void k_fillcsr(const int* __restrict__ src, const int* __restrict__ dst,
                          int* __restrict__ cursor, u32* __restrict__ packed, int E) {
    int e = gtid();
    if (e < E) {
        int t = dst[e];
        int pos = atomicAdd(&cursor[t], 1);
        packed[pos] = (u32)src[e];
    }
}

// ---------- layer 0 (rank-1 shortcut) ----------
// S[v] = dinv[v]*(dinv[v] + sum_e dinv[src]); x[v,:] = relu(S*W0+b0) bf16
__global__ __launch_bounds__(256) void k_sl0(const int* __restrict__ rowptr,
                                             const u32* __restrict__ packed,
                                             const float* __restrict__ dinv,
                                             const float* __restrict__ W0,
                                             const float* __restrict__ b0,
                                             u16* __restrict__ x, int N) {
    int lane = threadIdx.x & 31;
    int v = (blockIdx.x * 256 + threadIdx.x) >> 5;
    if (v >= N) return;
    int r0 = rowptr[v], r1 = rowptr[v + 1];
    float s = 0.0f;
    for (int j = r0 + lane; j < r1; j += 32) s += dinv[packed[j]];
#pragma unroll
    for (int off = 16; off > 0; off >>= 1) s += __shfl_xor(s, off, 32);
    float di = dinv[v];
    s = di * (di + s);
    int d0 = lane * 4;
    float4 w = *(const float4*)&W0[d0];
    float4 b = *(const float4*)&b0[d0];
    float a0 = fmaxf(fmaf(s, w.x, b.x), 0.0f);
    float a1 = fmaxf(fmaf(s, w.y, b.y), 0.0f);
    float a2 = fmaxf(fmaf(s, w.z, b.z), 0.0f);
    float a3 = fmaxf(fmaf(s, w.w, b.w), 0.0f);
    uint2 o;
    o.x = (u32)f2bf(a0) | ((u32)f2bf(a1) << 16);
    o.y = (u32)f2bf(a2) | ((u32)f2bf(a3) << 16);
    *(uint2*)&x[(size_t)v * HID + d0] = o;
}

// ---------- W -> bf16 transposed + XOR-swizzled (one-shot) ----------
__global__ __launch_bounds__(256) void k_wt(const float* __restrict__ W,
                                            u16* __restrict__ Wt) {
    int t = gtid();               // 0..2047
    if (t >= 2048) return;
    int n = t >> 4;               // output row (col of W)
    int j = t & 15;               // 16B block index along k
    int js = j ^ (n & 7);
    u32 w0 = (u32)f2bf(W[(j * 8 + 0) * HID + n]) | ((u32)f2bf(W[(j * 8 + 1) * HID + n]) << 16);
    u32 w1 = (u32)f2bf(W[(j * 8 + 2) * HID + n]) | ((u32)f2bf(W[(j * 8 + 3) * HID + n]) << 16);
    u32 w2 = (u32)f2bf(W[(j * 8 + 4) * HID + n]) | ((u32)f2bf(W[(j * 8 + 5) * HID + n]) << 16);
    u32 w3 = (u32)f2bf(W[(j * 8 + 6) * HID + n]) | ((u32)f2bf(W[(j * 8 + 7) * HID + n]) << 16);
    uint4 o = make_uint4(w0, w1, w2, w3);
    *(uint4*)&Wt[(size_t)n * HID + js * 8] = o;
}

// ---------- MFMA GEMM with dinv-premultiplied output ----------
// q[row,:] = dinv[row] * (x[row,:] @ W)   (bf16 in/out, fp32 accum)
__global__ __launch_bounds__(256) void k_gemm(const u16* __restrict__ x,
                                              const u16* __restrict__ Wt,
                                              const float* __restrict__ dinv,
                                              u16* __restrict__ q, int nrows) {
    __shared__ u16 Wl[HID * HID];  // 32 KiB
    int tid = threadIdx.x;
    for (int i = tid; i < 2048; i += 256)
        *(uint4*)&Wl[i * 8] = *(const uint4*)&Wt[i * 8];

    int w = tid >> 6;
    int l = tid & 63;
    int R0 = blockIdx.x * 64 + w * 16;
    int arow = R0 + (l & 15);
    int koff = (l >> 4) * 8;

    short8 a[4];
#pragma unroll
    for (int kb = 0; kb < 4; ++kb) {
        if (arow < nrows)
            a[kb] = *(const short8*)&x[(size_t)arow * HID + kb * 32 + koff];
        else
            a[kb] = (short8)0;
    }
    __syncthreads();

    int colbase = l & 15;
    int rowq = (l >> 4) * 4;
    float dv[4];
#pragma unroll
    for (int i = 0; i < 4; ++i) {
        int orow = R0 + rowq + i;
        dv[i] = (orow < nrows) ? dinv[orow] : 0.0f;
    }
#pragma unroll
    for (int cb = 0; cb < 8; ++cb) {
        f32x4 acc = {0.0f, 0.0f, 0.0f, 0.0f};
        int wrow = cb * 16 + (l & 15);
#pragma unroll
        for (int kb = 0; kb < 4; ++kb) {
            int j = (kb * 4 + (l >> 4)) ^ (wrow & 7);
            short8 b = *(const short8*)&Wl[wrow * HID + j * 8];
            acc = __builtin_amdgcn_mfma_f32_16x16x32_bf16(a[kb], b, acc, 0, 0, 0);
        }
#pragma unroll
        for (int i = 0; i < 4; ++i) {
            int orow = R0 + rowq + i;
            if (orow < nrows)
                q[(size_t)orow * HID + cb * 16 + colbase] = f2bf(acc[i] * dv[i]);
        }
    }
}

// ---------- fused aggregation (unweighted q-sum) ----------
// y[v,:] = relu( dinv[v]*(q[v,:] + sum_e q[src_e,:]) + b )
// 32-lane group per node; 2 edges/iter: half h (lanes 16h..16h+15) handles edge 2k+h,
// each lane owns 8 dims via uint4(8 bf16) gathers; halves combined by shfl_xor(16).
__global__ __launch_bounds__(256) void k_aggr(const u32* __restrict__ packed,
                                              const int* __restrict__ rowptr,
                                              const u16* __restrict__ q,
                                              const float* __restrict__ dinv,
                                              const float* __restrict__ b,
                                              u16* __restrict__ y, int N) {
    int lane = threadIdx.x & 31;
    int v = (blockIdx.x * 256 + threadIdx.x) >> 5;
    if (v >= N) return;
    int r0 = rowptr[v], r1 = rowptr[v + 1];
    int half = lane >> 4;
    int d8 = (lane & 15) * 8;

    float acc[8];
    if (half == 0) {
        uint4 qv = *(const uint4*)&q[(size_t)v * HID + d8];
        bf8_unpack(qv, acc);
    } else {
#pragma unroll
        for (int j = 0; j < 8; ++j) acc[j] = 0.0f;
    }

    for (int base = r0; base < r1; base += 32) {
        int idx = base + lane;
        u32 e = (idx < r1) ? packed[idx] : 0xFFFFFFFFu;
        int m = r1 - base; if (m > 32) m = 32;
        int iters = (m + 1) >> 1;
        for (int k = 0; k < iters; ++k) {
            u32 s = __shfl(e, 2 * k + half, 32);
            if (s != 0xFFFFFFFFu) {
                uint4 hq = *(const uint4*)&q[(size_t)s * HID + d8];
                float f[8];
                bf8_unpack(hq, f);
#pragma unroll
                for (int j = 0; j < 8; ++j) acc[j] += f[j];
            }
        }
    }
#pragma unroll
    for (int j = 0; j < 8; ++j) acc[j] += __shfl_xor(acc[j], 16, 32);

    if (half == 0) {
        float dv = dinv[v];
        float4 b0 = *(const float4*)&b[d8];
        float4 b1 = *(const float4*)&b[d8 + 4];
        float o[8];
        o[0] = fmaxf(fmaf(acc[0], dv, b0.x), 0.0f);
        o[1] = fmaxf(fmaf(acc[1], dv, b0.y), 0.0f);
        o[2] = fmaxf(fmaf(acc[2], dv, b0.z), 0.0f);
        o[3] = fmaxf(fmaf(acc[3], dv, b0.w), 0.0f);
        o[4] = fmaxf(fmaf(acc[4], dv, b1.x), 0.0f);
        o[5] = fmaxf(fmaf(acc[5], dv, b1.y), 0.0f);
        o[6] = fmaxf(fmaf(acc[6], dv, b1.z), 0.0f);
        o[7] = fmaxf(fmaf(acc[7], dv, b1.w), 0.0f);
        uint4 u;
        u.x = (u32)f2bf(o[0]) | ((u32)f2bf(o[1]) << 16);
        u.y = (u32)f2bf(o[2]) | ((u32)f2bf(o[3]) << 16);
        u.z = (u32)f2bf(o[4]) | ((u32)f2bf(o[5]) << 16);
        u.w = (u32)f2bf(o[6]) | ((u32)f2bf(o[7]) << 16);
        *(uint4*)&y[(size_t)v * HID + d8] = u;
    }
}

// ---------- pooling + head ----------

__global__ void k_pool(const u16* __restrict__ x, const int* __restrict__ batch,
                       float* __restrict__ pooled, float* __restrict__ cnt, int N) {
    const int K = 32;
    int d = threadIdx.x & (HID - 1);
    int chunk = blockIdx.x * 2 + (threadIdx.x >> 7);
    int v0 = chunk * K;
    if (v0 >= N) return;
    int vend = v0 + K; if (vend > N) vend = N;
    int g = batch[v0];
    float acc = 0.0f, c = 0.0f;
    for (int v = v0; v < vend; ++v) {
        int gv = batch[v];
        if (gv != g) {
            atomicAdd(&pooled[g * HID + d], acc);
            if (d == 0) atomicAdd(&cnt[g], c);
            acc = 0.0f; c = 0.0f; g = gv;
        }
        acc += bf2f((u32)x[(size_t)v * HID + d]);
        c += 1.0f;
    }
    atomicAdd(&pooled[g * HID + d], acc);
    if (d == 0) atomicAdd(&cnt[g], c);
}

__global__ void k_head(const float* __restrict__ pooled, const float* __restrict__ cnt,
                       const float* __restrict__ Wp, const float* __restrict__ bp,
                       float* __restrict__ out) {
    int g = gtid();
    if (g >= NG) return;
    float inv = 1.0f / fmaxf(cnt[g], 1.0f);
    float l[NC];
#pragma unroll
    for (int c = 0; c < NC; ++c) l[c] = bp[c];
    for (int d = 0; d < HID; ++d) {
        float pv = pooled[g * HID + d] * inv;
#pragma unroll
        for (int c = 0; c < NC; ++c) l[c] = fmaf(pv, Wp[d * NC + c], l[c]);
    }
    float m = l[0];
#pragma unroll
    for (int c = 1; c < NC; ++c) m = fmaxf(m, l[c]);
    float s = 0.0f;
#pragma unroll
    for (int c = 0; c < NC; ++c) s += expf(l[c] - m);
    float ls = logf(s) + m;
#pragma unroll
    for (int c = 0; c < NC; ++c) out[g * NC + c] = l[c] - ls;
}

extern "C" void kernel_launch(void* const* d_in, const int* in_sizes, int n_in,
                              void* d_out, int out_size, void* d_ws, size_t ws_size,
                              hipStream_t stream) {
    const int* ei    = (const int*)d_in[0];
    int E            = in_sizes[0] / 2;
    const int* src   = ei;
    const int* dstp  = ei + E;
    const int* batch = (const int*)d_in[1];
    int N            = in_sizes[1];
    const float* W0  = (const float*)d_in[2];
    const float* b0  = (const float*)d_in[3];
    const float* W1  = (const float*)d_in[4];
    const float* b1  = (const float*)d_in[5];
    const float* W2  = (const float*)d_in[6];
    const float* b2  = (const float*)d_in[7];
    const float* Wp  = (const float*)d_in[8];
    const float* bp  = (const float*)d_in[9];
    float* out       = (float*)d_out;

    // workspace layout
    u16*  xA     = (u16*)d_ws;                    // N*HID bf16
    u16*  xB     = xA + (size_t)N * HID;          // N*HID bf16
    u32*  packed = (u32*)(xB + (size_t)N * HID);  // E u32 (src only)
    u16*  Wt1    = (u16*)(packed + E);            // 128*128 bf16
    u16*  Wt2    = Wt1 + HID * HID;               // 128*128 bf16
    int*  cnt_i  = (int*)(Wt2 + HID * HID);       // N
    int*  rowptr = cnt_i + N;                     // N+1
    int*  cursor = rowptr + N + 1;                // N
    int*  partial= cursor + N;                    // 256
    float* dinv  = (float*)(partial + 256);       // N
    float* pooled= dinv + N;                      // NG*HID
    float* cntg  = pooled + NG * HID;             // NG

    auto cdiv = [](int a, int b) { return (a + b - 1) / b; };
    int B = cdiv(N, SCHUNK);

    hipMemsetAsync(cnt_i, 0, N * sizeof(int), stream);
    hipMemsetAsync(pooled, 0, (NG * HID + NG) * sizeof(float), stream);

    // CSR build + normalization
    k_hist<<<cdiv(E, 256), 256, 0, stream>>>(dstp, cnt_i, E);
    k_scan1<<<B, 256, 0, stream>>>(cnt_i, partial, N);
    k_scan2<<<1, 256, 0, stream>>>(partial, B);
    k_scan3<<<B, 256, 0, stream>>>(cnt_i, partial, rowptr, dinv, N);
    hipMemcpyAsync(cursor, rowptr, N * sizeof(int), hipMemcpyDeviceToDevice, stream);
    k_fillcsr<<<cdiv(E, 256), 256, 0, stream>>>(src, dstp, cursor, packed, E);

    // weight prep (bf16, transposed, swizzled)
    k_wt<<<8, 256, 0, stream>>>(W1, Wt1);
    k_wt<<<8, 256, 0, stream>>>(W2, Wt2);

    // layer 0 (rank-1 shortcut)
    k_sl0<<<cdiv(N, 8), 256, 0, stream>>>(rowptr, packed, dinv, W0, b0, xA, N);

    // layer 1: q = dinv*(xA@W1); xA = relu(dinv*(q[v]+sum q[src]) + b1)
    k_gemm<<<cdiv(N, 64), 256, 0, stream>>>(xA, Wt1, dinv, xB, N);
    k_aggr<<<cdiv(N, 8), 256, 0, stream>>>(packed, rowptr, xB, dinv, b1, xA, N);

    // layer 2
    k_gemm<<<cdiv(N, 64), 256, 0, stream>>>(xA, Wt2, dinv, xB, N);
    k_aggr<<<cdiv(N, 8), 256, 0, stream>>>(packed, rowptr, xB, dinv, b2, xA, N);

    // pooling + head
    k_pool<<<cdiv(cdiv(N, 32), 2), 256, 0, stream>>>(xA, batch, pooled, cntg, N);
    k_head<<<2, 256, 0, stream>>>(pooled, cntg, Wp, bp, out);
}

// Round 6
// 333.063 us; speedup vs baseline: 1.2291x; 1.2291x over previous
//
#include <hip/hip_runtime.h>

#define HID 128
#define NG 512
#define NC 10
#define SCHUNK 512
#define BSH 9                 // bucket = dst >> BSH (512 nodes per bucket)
#define TILE 4096             // edges per k_part1 block

typedef unsigned int u32;
typedef unsigned short u16;
typedef __attribute__((ext_vector_type(8))) short short8;
typedef __attribute__((ext_vector_type(4))) float f32x4;

static __device__ __forceinline__ int gtid() {
    return blockIdx.x * blockDim.x + threadIdx.x;
}

// bf16 helpers (RNE pack, exact unpack)
static __device__ __forceinline__ u16 f2bf(float f) {
    u32 u = __float_as_uint(f);
    u32 r = u + 0x7fffu + ((u >> 16) & 1u);
    return (u16)(r >> 16);
}
static __device__ __forceinline__ float bf2f(u32 s) {
    return __uint_as_float(s << 16);
}
static __device__ __forceinline__ void bf8_unpack(uint4 u, float* f) {
    f[0] = bf2f(u.x & 0xffffu); f[1] = bf2f(u.x >> 16);
    f[2] = bf2f(u.y & 0xffffu); f[3] = bf2f(u.y >> 16);
    f[4] = bf2f(u.z & 0xffffu); f[5] = bf2f(u.z >> 16);
    f[6] = bf2f(u.w & 0xffffu); f[7] = bf2f(u.w >> 16);
}

// ---------- degree + rowptr ----------

__global__ void k_hist(const int* __restrict__ dst, int* __restrict__ cnt, int E) {
    int i = gtid();
    if (i < E) atomicAdd(&cnt[dst[i]], 1);
}

__global__ __launch_bounds__(256) void k_scan1(const int* __restrict__ cnt,
                                               int* __restrict__ partial, int N) {
    __shared__ int s[256];
    int t = threadIdx.x;
    int i0 = blockIdx.x * SCHUNK + t * 2;
    int v = 0;
    if (i0 < N) v += cnt[i0];
    if (i0 + 1 < N) v += cnt[i0 + 1];
    s[t] = v;
    __syncthreads();
    for (int off = 128; off > 0; off >>= 1) {
        if (t < off) s[t] += s[t + off];
        __syncthreads();
    }
    if (t == 0) partial[blockIdx.x] = s[0];
}

__global__ __launch_bounds__(256) void k_scan2(int* __restrict__ partial, int B) {
    __shared__ int s[256];
    int t = threadIdx.x;
    int own = (t < B) ? partial[t] : 0;
    s[t] = own;
    __syncthreads();
    for (int off = 1; off < 256; off <<= 1) {
        int v = (t >= off) ? s[t - off] : 0;
        __syncthreads();
        s[t] += v;
        __syncthreads();
    }
    if (t < B) partial[t] = s[t] - own;  // exclusive
}

__global__ __launch_bounds__(256) void k_scan3(const int* __restrict__ cnt,
                                               const int* __restrict__ partial,
                                               int* __restrict__ rowptr,
                                               float* __restrict__ dinv, int N) {
    __shared__ int s[256];
    int t = threadIdx.x;
    int i0 = blockIdx.x * SCHUNK + t * 2;
    int c0 = 0, c1 = 0;
    if (i0 < N) c0 = cnt[i0];
    if (i0 + 1 < N) c1 = cnt[i0 + 1];
    int own = c0 + c1;
    s[t] = own;
    __syncthreads();
    for (int off = 1; off < 256; off <<= 1) {
        int v = (t >= off) ? s[t - off] : 0;
        __syncthreads();
        s[t] += v;
        __syncthreads();
    }
    int base = partial[blockIdx.x] + s[t] - own;
    if (i0 < N) { rowptr[i0] = base; dinv[i0] = rsqrtf(1.0f + (float)c0); }
    if (i0 + 1 < N) { rowptr[i0 + 1] = base + c0; dinv[i0 + 1] = rsqrtf(1.0f + (float)c1); }
    if (i0 >= N - 2 && i0 < N) rowptr[N] = base + own;
}

// ---------- two-pass dst-partition (CSR build without random scatter) ----------

// bucket cursors start at rowptr[bucket*512]
__global__ void k_binit(const int* __restrict__ rowptr, int* __restrict__ bcur, int NB) {
    int b = gtid();
    if (b < NB) bcur[b] = rowptr[b << BSH];
}

// pass 1: coarse partition into buckets of 512 nodes; writes advance sequentially per bucket
__global__ __launch_bounds__(256) void k_part1(const int* __restrict__ src,
                                               const int* __restrict__ dst,
                                               int* __restrict__ bcur,
                                               uint2* __restrict__ tmp, int E, int NB) {
    __shared__ int cnt[256];
    __shared__ int base[256];
    int t = threadIdx.x;
    int e0 = blockIdx.x * TILE;
    for (int i = t; i < NB; i += 256) cnt[i] = 0;
    __syncthreads();
    int s_[16], d_[16];
#pragma unroll
    for (int k = 0; k < 16; ++k) {
        int e = e0 + k * 256 + t;
        if (e < E) {
            s_[k] = src[e];
            d_[k] = dst[e];
            atomicAdd(&cnt[d_[k] >> BSH], 1);
        } else {
            d_[k] = -1;
        }
    }
    __syncthreads();
    for (int i = t; i < NB; i += 256) {
        base[i] = atomicAdd(&bcur[i], cnt[i]);
        cnt[i] = 0;
    }
    __syncthreads();
#pragma unroll
    for (int k = 0; k < 16; ++k) {
        if (d_[k] >= 0) {
            int b = d_[k] >> BSH;
            int pos = base[b] + atomicAdd(&cnt[b], 1);
            tmp[pos] = make_uint2((u32)s_[k], (u32)d_[k]);
        }
    }
}

// pass 2: within-bucket counting sort -> exact CSR (packed[pos] = src)
__global__ __launch_bounds__(512) void k_part2(const int* __restrict__ rowptr,
                                               const uint2* __restrict__ tmp,
                                               u32* __restrict__ packed, int N) {
    __shared__ int cur[1 << BSH];
    int b = blockIdx.x;
    int v0 = b << BSH;
    int nv = N - v0; if (nv > (1 << BSH)) nv = 1 << BSH;
    int t = threadIdx.x;
    for (int i = t; i < nv; i += 512) cur[i] = rowptr[v0 + i];
    __syncthreads();
    int e0 = rowptr[v0];
    int vend = v0 + nv;
    int e1 = rowptr[vend];
    for (int e = e0 + t; e < e1; e += 512) {
        uint2 p = tmp[e];
        int pos = atomicAdd(&cur[p.y & ((1 << BSH) - 1)], 1);
        packed[pos] = p.x;
    }
}

// ---------- layer 0 (rank-1 shortcut) ----------
// S[v] = dinv[v]*(dinv[v] + sum_e dinv[src]); x[v,:] = relu(S*W0+b0) bf16
__global__ __launch_bounds__(256) void k_sl0(const int* __restrict__ rowptr,
                                             const u32* __restrict__ packed,
                                             const float* __restrict__ dinv,
                                             const float* __restrict__ W0,
                                             const float* __restrict__ b0,
                                             u16* __restrict__ x, int N) {
    int lane = threadIdx.x & 31;
    int v = (blockIdx.x * 256 + threadIdx.x) >> 5;
    if (v >= N) return;
    int r0 = rowptr[v], r1 = rowptr[v + 1];
    float s = 0.0f;
    for (int j = r0 + lane; j < r1; j += 32) s += dinv[packed[j]];
#pragma unroll
    for (int off = 16; off > 0; off >>= 1) s += __shfl_xor(s, off, 32);
    float di = dinv[v];
    s = di * (di + s);
    int d0 = lane * 4;
    float4 w = *(const float4*)&W0[d0];
    float4 b = *(const float4*)&b0[d0];
    float a0 = fmaxf(fmaf(s, w.x, b.x), 0.0f);
    float a1 = fmaxf(fmaf(s, w.y, b.y), 0.0f);
    float a2 = fmaxf(fmaf(s, w.z, b.z), 0.0f);
    float a3 = fmaxf(fmaf(s, w.w, b.w), 0.0f);
    uint2 o;
    o.x = (u32)f2bf(a0) | ((u32)f2bf(a1) << 16);
    o.y = (u32)f2bf(a2) | ((u32)f2bf(a3) << 16);
    *(uint2*)&x[(size_t)v * HID + d0] = o;
}

// ---------- W -> bf16 transposed + XOR-swizzled (one-shot) ----------
__global__ __launch_bounds__(256) void k_wt(const float* __restrict__ W,
                                            u16* __restrict__ Wt) {
    int t = gtid();               // 0..2047
    if (t >= 2048) return;
    int n = t >> 4;               // output row (col of W)
    int j = t & 15;               // 16B block index along k
    int js = j ^ (n & 7);
    u32 w0 = (u32)f2bf(W[(j * 8 + 0) * HID + n]) | ((u32)f2bf(W[(j * 8 + 1) * HID + n]) << 16);
    u32 w1 = (u32)f2bf(W[(j * 8 + 2) * HID + n]) | ((u32)f2bf(W[(j * 8 + 3) * HID + n]) << 16);
    u32 w2 = (u32)f2bf(W[(j * 8 + 4) * HID + n]) | ((u32)f2bf(W[(j * 8 + 5) * HID + n]) << 16);
    u32 w3 = (u32)f2bf(W[(j * 8 + 6) * HID + n]) | ((u32)f2bf(W[(j * 8 + 7) * HID + n]) << 16);
    uint4 o = make_uint4(w0, w1, w2, w3);
    *(uint4*)&Wt[(size_t)n * HID + js * 8] = o;
}

// ---------- MFMA GEMM with dinv-premultiplied output ----------
// q[row,:] = dinv[row] * (x[row,:] @ W)   (bf16 in/out, fp32 accum)
__global__ __launch_bounds__(256) void k_gemm(const u16* __restrict__ x,
                                              const u16* __restrict__ Wt,
                                              const float* __restrict__ dinv,
                                              u16* __restrict__ q, int nrows) {
    __shared__ u16 Wl[HID * HID];  // 32 KiB
    int tid = threadIdx.x;
    for (int i = tid; i < 2048; i += 256)
        *(uint4*)&Wl[i * 8] = *(const uint4*)&Wt[i * 8];

    int w = tid >> 6;
    int l = tid & 63;
    int R0 = blockIdx.x * 64 + w * 16;
    int arow = R0 + (l & 15);
    int koff = (l >> 4) * 8;

    short8 a[4];
#pragma unroll
    for (int kb = 0; kb < 4; ++kb) {
        if (arow < nrows)
            a[kb] = *(const short8*)&x[(size_t)arow * HID + kb * 32 + koff];
        else
            a[kb] = (short8)0;
    }
    __syncthreads();

    int colbase = l & 15;
    int rowq = (l >> 4) * 4;
    float dv[4];
#pragma unroll
    for (int i = 0; i < 4; ++i) {
        int orow = R0 + rowq + i;
        dv[i] = (orow < nrows) ? dinv[orow] : 0.0f;
    }
#pragma unroll
    for (int cb = 0; cb < 8; ++cb) {
        f32x4 acc = {0.0f, 0.0f, 0.0f, 0.0f};
        int wrow = cb * 16 + (l & 15);
#pragma unroll
        for (int kb = 0; kb < 4; ++kb) {
            int j = (kb * 4 + (l >> 4)) ^ (wrow & 7);
            short8 b = *(const short8*)&Wl[wrow * HID + j * 8];
            acc = __builtin_amdgcn_mfma_f32_16x16x32_bf16(a[kb], b, acc, 0, 0, 0);
        }
#pragma unroll
        for (int i = 0; i < 4; ++i) {
            int orow = R0 + rowq + i;
            if (orow < nrows)
                q[(size_t)orow * HID + cb * 16 + colbase] = f2bf(acc[i] * dv[i]);
        }
    }
}

// ---------- fused aggregation (unweighted q-sum) ----------
// y[v,:] = relu( dinv[v]*(q[v,:] + sum_e q[src_e,:]) + b )
__global__ __launch_bounds__(256) void k_aggr(const u32* __restrict__ packed,
                                              const int* __restrict__ rowptr,
                                              const u16* __restrict__ q,
                                              const float* __restrict__ dinv,
                                              const float* __restrict__ b,
                                              u16* __restrict__ y, int N) {
    int lane = threadIdx.x & 31;
    int v = (blockIdx.x * 256 + threadIdx.x) >> 5;
    if (v >= N) return;
    int r0 = rowptr[v], r1 = rowptr[v + 1];
    int half = lane >> 4;
    int d8 = (lane & 15) * 8;

    float acc[8];
    if (half == 0) {
        uint4 qv = *(const uint4*)&q[(size_t)v * HID + d8];
        bf8_unpack(qv, acc);
    } else {
#pragma unroll
        for (int j = 0; j < 8; ++j) acc[j] = 0.0f;
    }

    for (int base = r0; base < r1; base += 32) {
        int idx = base + lane;
        u32 e = (idx < r1) ? packed[idx] : 0xFFFFFFFFu;
        int m = r1 - base; if (m > 32) m = 32;
        int iters = (m + 1) >> 1;
        for (int k = 0; k < iters; ++k) {
            u32 s = __shfl(e, 2 * k + half, 32);
            if (s != 0xFFFFFFFFu) {
                uint4 hq = *(const uint4*)&q[(size_t)s * HID + d8];
                float f[8];
                bf8_unpack(hq, f);
#pragma unroll
                for (int j = 0; j < 8; ++j) acc[j] += f[j];
            }
        }
    }
#pragma unroll
    for (int j = 0; j < 8; ++j) acc[j] += __shfl_xor(acc[j], 16, 32);

    if (half == 0) {
        float dv = dinv[v];
        float4 b0 = *(const float4*)&b[d8];
        float4 b1 = *(const float4*)&b[d8 + 4];
        float o[8];
        o[0] = fmaxf(fmaf(acc[0], dv, b0.x), 0.0f);
        o[1] = fmaxf(fmaf(acc[1], dv, b0.y), 0.0f);
        o[2] = fmaxf(fmaf(acc[2], dv, b0.z), 0.0f);
        o[3] = fmaxf(fmaf(acc[3], dv, b0.w), 0.0f);
        o[4] = fmaxf(fmaf(acc[4], dv, b1.x), 0.0f);
        o[5] = fmaxf(fmaf(acc[5], dv, b1.y), 0.0f);
        o[6] = fmaxf(fmaf(acc[6], dv, b1.z), 0.0f);
        o[7] = fmaxf(fmaf(acc[7], dv, b1.w), 0.0f);
        uint4 u;
        u.x = (u32)f2bf(o[0]) | ((u32)f2bf(o[1]) << 16);
        u.y = (u32)f2bf(o[2]) | ((u32)f2bf(o[3]) << 16);
        u.z = (u32)f2bf(o[4]) | ((u32)f2bf(o[5]) << 16);
        u.w = (u32)f2bf(o[6]) | ((u32)f2bf(o[7]) << 16);
        *(uint4*)&y[(size_t)v * HID + d8] = u;
    }
}

// ---------- pooling + head ----------

__global__ void k_pool(const u16* __restrict__ x, const int* __restrict__ batch,
                       float* __restrict__ pooled, float* __restrict__ cnt, int N) {
    const int K = 32;
    int d = threadIdx.x & (HID - 1);
    int chunk = blockIdx.x * 2 + (threadIdx.x >> 7);
    int v0 = chunk * K;
    if (v0 >= N) return;
    int vend = v0 + K; if (vend > N) vend = N;
    int g = batch[v0];
    float acc = 0.0f, c = 0.0f;
    for (int v = v0; v < vend; ++v) {
        int gv = batch[v];
        if (gv != g) {
            atomicAdd(&pooled[g * HID + d], acc);
            if (d == 0) atomicAdd(&cnt[g], c);
            acc = 0.0f; c = 0.0f; g = gv;
        }
        acc += bf2f((u32)x[(size_t)v * HID + d]);
        c += 1.0f;
    }
    atomicAdd(&pooled[g * HID + d], acc);
    if (d == 0) atomicAdd(&cnt[g], c);
}

__global__ void k_head(const float* __restrict__ pooled, const float* __restrict__ cnt,
                       const float* __restrict__ Wp, const float* __restrict__ bp,
                       float* __restrict__ out) {
    int g = gtid();
    if (g >= NG) return;
    float inv = 1.0f / fmaxf(cnt[g], 1.0f);
    float l[NC];
#pragma unroll
    for (int c = 0; c < NC; ++c) l[c] = bp[c];
    for (int d = 0; d < HID; ++d) {
        float pv = pooled[g * HID + d] * inv;
#pragma unroll
        for (int c = 0; c < NC; ++c) l[c] = fmaf(pv, Wp[d * NC + c], l[c]);
    }
    float m = l[0];
#pragma unroll
    for (int c = 1; c < NC; ++c) m = fmaxf(m, l[c]);
    float s = 0.0f;
#pragma unroll
    for (int c = 0; c < NC; ++c) s += expf(l[c] - m);
    float ls = logf(s) + m;
#pragma unroll
    for (int c = 0; c < NC; ++c) out[g * NC + c] = l[c] - ls;
}

extern "C" void kernel_launch(void* const* d_in, const int* in_sizes, int n_in,
                              void* d_out, int out_size, void* d_ws, size_t ws_size,
                              hipStream_t stream) {
    const int* ei    = (const int*)d_in[0];
    int E            = in_sizes[0] / 2;
    const int* src   = ei;
    const int* dstp  = ei + E;
    const int* batch = (const int*)d_in[1];
    int N            = in_sizes[1];
    const float* W0  = (const float*)d_in[2];
    const float* b0  = (const float*)d_in[3];
    const float* W1  = (const float*)d_in[4];
    const float* b1  = (const float*)d_in[5];
    const float* W2  = (const float*)d_in[6];
    const float* b2  = (const float*)d_in[7];
    const float* Wp  = (const float*)d_in[8];
    const float* bp  = (const float*)d_in[9];
    float* out       = (float*)d_out;

    // workspace layout
    u16*  xA     = (u16*)d_ws;                    // N*HID bf16
    u16*  xB     = xA + (size_t)N * HID;          // N*HID bf16
    u32*  packed = (u32*)(xB + (size_t)N * HID);  // E u32 (src per CSR slot)
    uint2* tmp   = (uint2*)(packed + E);          // E uint2 (bucket-partitioned {src,dst})
    u16*  Wt1    = (u16*)(tmp + E);               // 128*128 bf16
    u16*  Wt2    = Wt1 + HID * HID;               // 128*128 bf16
    int*  cnt_i  = (int*)(Wt2 + HID * HID);       // N
    int*  rowptr = cnt_i + N;                     // N+1
    int*  bcur   = rowptr + N + 1;                // NB
    int*  partial= bcur + 256;                    // 256
    float* dinv  = (float*)(partial + 256);       // N
    float* pooled= dinv + N;                      // NG*HID
    float* cntg  = pooled + NG * HID;             // NG

    auto cdiv = [](int a, int b) { return (a + b - 1) / b; };
    int B  = cdiv(N, SCHUNK);
    int NB = cdiv(N, 1 << BSH);                   // 196 buckets

    hipMemsetAsync(cnt_i, 0, N * sizeof(int), stream);
    hipMemsetAsync(pooled, 0, (NG * HID + NG) * sizeof(float), stream);

    // degree + rowptr + dinv
    k_hist<<<cdiv(E, 256), 256, 0, stream>>>(dstp, cnt_i, E);
    k_scan1<<<B, 256, 0, stream>>>(cnt_i, partial, N);
    k_scan2<<<1, 256, 0, stream>>>(partial, B);
    k_scan3<<<B, 256, 0, stream>>>(cnt_i, partial, rowptr, dinv, N);

    // two-pass CSR build
    k_binit<<<1, 256, 0, stream>>>(rowptr, bcur, NB);
    k_part1<<<cdiv(E, TILE), 256, 0, stream>>>(src, dstp, bcur, tmp, E, NB);
    k_part2<<<NB, 512, 0, stream>>>(rowptr, tmp, packed, N);

    // weight prep (bf16, transposed, swizzled)
    k_wt<<<8, 256, 0, stream>>>(W1, Wt1);
    k_wt<<<8, 256, 0, stream>>>(W2, Wt2);

    // layer 0 (rank-1 shortcut)
    k_sl0<<<cdiv(N, 8), 256, 0, stream>>>(rowptr, packed, dinv, W0, b0, xA, N);

    // layer 1: q = dinv*(xA@W1); xA = relu(dinv*(q[v]+sum q[src]) + b1)
    k_gemm<<<cdiv(N, 64), 256, 0, stream>>>(xA, Wt1, dinv, xB, N);
    k_aggr<<<cdiv(N, 8), 256, 0, stream>>>(packed, rowptr, xB, dinv, b1, xA, N);

    // layer 2
    k_gemm<<<cdiv(N, 64), 256, 0, stream>>>(xA, Wt2, dinv, xB, N);
    k_aggr<<<cdiv(N, 8), 256, 0, stream>>>(packed, rowptr, xB, dinv, b2, xA, N);

    // pooling + head
    k_pool<<<cdiv(cdiv(N, 32), 2), 256, 0, stream>>>(xA, batch, pooled, cntg, N);
    k_head<<<2, 256, 0, stream>>>(pooled, cntg, Wp, bp, out);
}

// Round 7
// 281.374 us; speedup vs baseline: 1.4549x; 1.1837x over previous
//
#include <hip/hip_runtime.h>

#define HID 128
#define NG 512
#define NC 10
#define BSH 9                 // bucket = dst >> BSH (512 nodes per bucket)
#define BSZ (1 << BSH)
#define TILE 4096             // edges per k_part1/k_bhist block

typedef unsigned int u32;
typedef unsigned short u16;
typedef __attribute__((ext_vector_type(8))) short short8;
typedef __attribute__((ext_vector_type(4))) float f32x4;

static __device__ __forceinline__ int gtid() {
    return blockIdx.x * blockDim.x + threadIdx.x;
}

// bf16 helpers (RNE pack, exact unpack)
static __device__ __forceinline__ u16 f2bf(float f) {
    u32 u = __float_as_uint(f);
    u32 r = u + 0x7fffu + ((u >> 16) & 1u);
    return (u16)(r >> 16);
}
static __device__ __forceinline__ float bf2f(u32 s) {
    return __uint_as_float(s << 16);
}
static __device__ __forceinline__ void bf8_unpack(uint4 u, float* f) {
    f[0] = bf2f(u.x & 0xffffu); f[1] = bf2f(u.x >> 16);
    f[2] = bf2f(u.y & 0xffffu); f[3] = bf2f(u.y >> 16);
    f[4] = bf2f(u.z & 0xffffu); f[5] = bf2f(u.z >> 16);
    f[6] = bf2f(u.w & 0xffffu); f[7] = bf2f(u.w >> 16);
}

// ---------- bucket-level histogram (196 counters; LDS pre-aggregated) ----------
__global__ __launch_bounds__(256) void k_bhist(const int* __restrict__ dst,
                                               int* __restrict__ bcnt, int E, int NB) {
    __shared__ int cnt[256];
    int t = threadIdx.x;
    int e0 = blockIdx.x * TILE;
    for (int i = t; i < NB; i += 256) cnt[i] = 0;
    __syncthreads();
#pragma unroll
    for (int k = 0; k < 16; ++k) {
        int e = e0 + k * 256 + t;
        if (e < E) atomicAdd(&cnt[dst[e] >> BSH], 1);
    }
    __syncthreads();
    for (int i = t; i < NB; i += 256)
        if (cnt[i] > 0) atomicAdd(&bcnt[i], cnt[i]);
}

// exclusive scan of bucket counts -> bbase[NB+1]; init bcur
__global__ __launch_bounds__(256) void k_bscan(const int* __restrict__ bcnt,
                                               int* __restrict__ bbase,
                                               int* __restrict__ bcur, int NB, int E) {
    __shared__ int s[256];
    int t = threadIdx.x;
    int own = (t < NB) ? bcnt[t] : 0;
    s[t] = own;
    __syncthreads();
    for (int off = 1; off < 256; off <<= 1) {
        int v = (t >= off) ? s[t - off] : 0;
        __syncthreads();
        s[t] += v;
        __syncthreads();
    }
    if (t < NB) {
        int b = s[t] - own;
        bbase[t] = b;
        bcur[t] = b;
    }
    if (t == 0) bbase[NB] = E;
}

// pass 1: coarse partition into buckets; writes advance sequentially per bucket
__global__ __launch_bounds__(256) void k_part1(const int* __restrict__ src,
                                               const int* __restrict__ dst,
                                               int* __restrict__ bcur,
                                               uint2* __restrict__ tmp, int E, int NB) {
    __shared__ int cnt[256];
    __shared__ int base[256];
    int t = threadIdx.x;
    int e0 = blockIdx.x * TILE;
    for (int i = t; i < NB; i += 256) cnt[i] = 0;
    __syncthreads();
    int s_[16], d_[16];
#pragma unroll
    for (int k = 0; k < 16; ++k) {
        int e = e0 + k * 256 + t;
        if (e < E) {
            s_[k] = src[e];
            d_[k] = dst[e];
            atomicAdd(&cnt[d_[k] >> BSH], 1);
        } else {
            d_[k] = -1;
        }
    }
    __syncthreads();
    for (int i = t; i < NB; i += 256) {
        if (cnt[i] > 0) base[i] = atomicAdd(&bcur[i], cnt[i]);
        cnt[i] = 0;
    }
    __syncthreads();
#pragma unroll
    for (int k = 0; k < 16; ++k) {
        if (d_[k] >= 0) {
            int b = d_[k] >> BSH;
            int pos = base[b] + atomicAdd(&cnt[b], 1);
            tmp[pos] = make_uint2((u32)s_[k], (u32)d_[k]);
        }
    }
}

// pass 2: per bucket: LDS per-node degree + scan -> rowptr/dinv (fused), counting sort -> packed
__global__ __launch_bounds__(512) void k_part2(const int* __restrict__ bbase,
                                               const uint2* __restrict__ tmp,
                                               u32* __restrict__ packed,
                                               int* __restrict__ rowptr,
                                               float* __restrict__ dinv,
                                               int N, int NB) {
    __shared__ int cnt[BSZ];
    __shared__ int scn[BSZ];
    __shared__ int cur[BSZ];
    int b = blockIdx.x;
    int v0 = b << BSH;
    int nv = N - v0; if (nv > BSZ) nv = BSZ;
    int t = threadIdx.x;
    int e0 = bbase[b], e1 = bbase[b + 1];

    cnt[t] = 0;
    __syncthreads();
    for (int e = e0 + t; e < e1; e += 512)
        atomicAdd(&cnt[tmp[e].y & (BSZ - 1)], 1);
    __syncthreads();
    int own = cnt[t];
    scn[t] = own;
    __syncthreads();
    for (int off = 1; off < BSZ; off <<= 1) {
        int v = (t >= off) ? scn[t - off] : 0;
        __syncthreads();
        scn[t] += v;
        __syncthreads();
    }
    int start = e0 + scn[t] - own;   // exclusive
    cur[t] = start;
    if (t < nv) {
        rowptr[v0 + t] = start;
        dinv[v0 + t] = rsqrtf(1.0f + (float)own);
    }
    if (b == NB - 1 && t == 0) rowptr[N] = e1;
    __syncthreads();
    for (int e = e0 + t; e < e1; e += 512) {
        uint2 p = tmp[e];
        int pos = atomicAdd(&cur[p.y & (BSZ - 1)], 1);
        packed[pos] = p.x;
    }
}

// ---------- layer 0 (rank-1 shortcut) ----------
// S[v] = dinv[v]*(dinv[v] + sum_e dinv[src]); x[v,:] = relu(S*W0+b0) bf16
__global__ __launch_bounds__(256) void k_sl0(const int* __restrict__ rowptr,
                                             const u32* __restrict__ packed,
                                             const float* __restrict__ dinv,
                                             const float* __restrict__ W0,
                                             const float* __restrict__ b0,
                                             u16* __restrict__ x, int N) {
    int lane = threadIdx.x & 31;
    int v = (blockIdx.x * 256 + threadIdx.x) >> 5;
    if (v >= N) return;
    int r0 = rowptr[v], r1 = rowptr[v + 1];
    float s = 0.0f;
    for (int j = r0 + lane; j < r1; j += 32) s += dinv[packed[j]];
#pragma unroll
    for (int off = 16; off > 0; off >>= 1) s += __shfl_xor(s, off, 32);
    float di = dinv[v];
    s = di * (di + s);
    int d0 = lane * 4;
    float4 w = *(const float4*)&W0[d0];
    float4 b = *(const float4*)&b0[d0];
    float a0 = fmaxf(fmaf(s, w.x, b.x), 0.0f);
    float a1 = fmaxf(fmaf(s, w.y, b.y), 0.0f);
    float a2 = fmaxf(fmaf(s, w.z, b.z), 0.0f);
    float a3 = fmaxf(fmaf(s, w.w, b.w), 0.0f);
    uint2 o;
    o.x = (u32)f2bf(a0) | ((u32)f2bf(a1) << 16);
    o.y = (u32)f2bf(a2) | ((u32)f2bf(a3) << 16);
    *(uint2*)&x[(size_t)v * HID + d0] = o;
}

// ---------- W -> bf16 transposed + XOR-swizzled (one-shot) ----------
__global__ __launch_bounds__(256) void k_wt(const float* __restrict__ W,
                                            u16* __restrict__ Wt) {
    int t = gtid();               // 0..2047
    if (t >= 2048) return;
    int n = t >> 4;               // output row (col of W)
    int j = t & 15;               // 16B block index along k
    int js = j ^ (n & 7);
    u32 w0 = (u32)f2bf(W[(j * 8 + 0) * HID + n]) | ((u32)f2bf(W[(j * 8 + 1) * HID + n]) << 16);
    u32 w1 = (u32)f2bf(W[(j * 8 + 2) * HID + n]) | ((u32)f2bf(W[(j * 8 + 3) * HID + n]) << 16);
    u32 w2 = (u32)f2bf(W[(j * 8 + 4) * HID + n]) | ((u32)f2bf(W[(j * 8 + 5) * HID + n]) << 16);
    u32 w3 = (u32)f2bf(W[(j * 8 + 6) * HID + n]) | ((u32)f2bf(W[(j * 8 + 7) * HID + n]) << 16);
    uint4 o = make_uint4(w0, w1, w2, w3);
    *(uint4*)&Wt[(size_t)n * HID + js * 8] = o;
}

// ---------- MFMA GEMM with dinv-premultiplied output ----------
// q[row,:] = dinv[row] * (x[row,:] @ W)   (bf16 in/out, fp32 accum)
__global__ __launch_bounds__(256) void k_gemm(const u16* __restrict__ x,
                                              const u16* __restrict__ Wt,
                                              const float* __restrict__ dinv,
                                              u16* __restrict__ q, int nrows) {
    __shared__ u16 Wl[HID * HID];  // 32 KiB
    int tid = threadIdx.x;
    for (int i = tid; i < 2048; i += 256)
        *(uint4*)&Wl[i * 8] = *(const uint4*)&Wt[i * 8];

    int w = tid >> 6;
    int l = tid & 63;
    int R0 = blockIdx.x * 64 + w * 16;
    int arow = R0 + (l & 15);
    int koff = (l >> 4) * 8;

    short8 a[4];
#pragma unroll
    for (int kb = 0; kb < 4; ++kb) {
        if (arow < nrows)
            a[kb] = *(const short8*)&x[(size_t)arow * HID + kb * 32 + koff];
        else
            a[kb] = (short8)0;
    }
    __syncthreads();

    int colbase = l & 15;
    int rowq = (l >> 4) * 4;
    float dv[4];
#pragma unroll
    for (int i = 0; i < 4; ++i) {
        int orow = R0 + rowq + i;
        dv[i] = (orow < nrows) ? dinv[orow] : 0.0f;
    }
#pragma unroll
    for (int cb = 0; cb < 8; ++cb) {
        f32x4 acc = {0.0f, 0.0f, 0.0f, 0.0f};
        int wrow = cb * 16 + (l & 15);
#pragma unroll
        for (int kb = 0; kb < 4; ++kb) {
            int j = (kb * 4 + (l >> 4)) ^ (wrow & 7);
            short8 b = *(const short8*)&Wl[wrow * HID + j * 8];
            acc = __builtin_amdgcn_mfma_f32_16x16x32_bf16(a[kb], b, acc, 0, 0, 0);
        }
#pragma unroll
        for (int i = 0; i < 4; ++i) {
            int orow = R0 + rowq + i;
            if (orow < nrows)
                q[(size_t)orow * HID + cb * 16 + colbase] = f2bf(acc[i] * dv[i]);
        }
    }
}

// ---------- fused aggregation (unweighted q-sum) ----------
// y[v,:] = relu( dinv[v]*(q[v,:] + sum_e q[src_e,:]) + b )
__global__ __launch_bounds__(256) void k_aggr(const u32* __restrict__ packed,
                                              const int* __restrict__ rowptr,
                                              const u16* __restrict__ q,
                                              const float* __restrict__ dinv,
                                              const float* __restrict__ b,
                                              u16* __restrict__ y, int N) {
    int lane = threadIdx.x & 31;
    int v = (blockIdx.x * 256 + threadIdx.x) >> 5;
    if (v >= N) return;
    int r0 = rowptr[v], r1 = rowptr[v + 1];
    int half = lane >> 4;
    int d8 = (lane & 15) * 8;

    float acc[8];
    if (half == 0) {
        uint4 qv = *(const uint4*)&q[(size_t)v * HID + d8];
        bf8_unpack(qv, acc);
    } else {
#pragma unroll
        for (int j = 0; j < 8; ++j) acc[j] = 0.0f;
    }

    for (int base = r0; base < r1; base += 32) {
        int idx = base + lane;
        u32 e = (idx < r1) ? packed[idx] : 0xFFFFFFFFu;
        int m = r1 - base; if (m > 32) m = 32;
        int iters = (m + 1) >> 1;
        for (int k = 0; k < iters; ++k) {
            u32 s = __shfl(e, 2 * k + half, 32);
            if (s != 0xFFFFFFFFu) {
                uint4 hq = *(const uint4*)&q[(size_t)s * HID + d8];
                float f[8];
                bf8_unpack(hq, f);
#pragma unroll
                for (int j = 0; j < 8; ++j) acc[j] += f[j];
            }
        }
    }
#pragma unroll
    for (int j = 0; j < 8; ++j) acc[j] += __shfl_xor(acc[j], 16, 32);

    if (half == 0) {
        float dv = dinv[v];
        float4 b0 = *(const float4*)&b[d8];
        float4 b1 = *(const float4*)&b[d8 + 4];
        float o[8];
        o[0] = fmaxf(fmaf(acc[0], dv, b0.x), 0.0f);
        o[1] = fmaxf(fmaf(acc[1], dv, b0.y), 0.0f);
        o[2] = fmaxf(fmaf(acc[2], dv, b0.z), 0.0f);
        o[3] = fmaxf(fmaf(acc[3], dv, b0.w), 0.0f);
        o[4] = fmaxf(fmaf(acc[4], dv, b1.x), 0.0f);
        o[5] = fmaxf(fmaf(acc[5], dv, b1.y), 0.0f);
        o[6] = fmaxf(fmaf(acc[6], dv, b1.z), 0.0f);
        o[7] = fmaxf(fmaf(acc[7], dv, b1.w), 0.0f);
        uint4 u;
        u.x = (u32)f2bf(o[0]) | ((u32)f2bf(o[1]) << 16);
        u.y = (u32)f2bf(o[2]) | ((u32)f2bf(o[3]) << 16);
        u.z = (u32)f2bf(o[4]) | ((u32)f2bf(o[5]) << 16);
        u.w = (u32)f2bf(o[6]) | ((u32)f2bf(o[7]) << 16);
        *(uint4*)&y[(size_t)v * HID + d8] = u;
    }
}

// ---------- pooling + head ----------

__global__ void k_pool(const u16* __restrict__ x, const int* __restrict__ batch,
                       float* __restrict__ pooled, float* __restrict__ cnt, int N) {
    const int K = 32;
    int d = threadIdx.x & (HID - 1);
    int chunk = blockIdx.x * 2 + (threadIdx.x >> 7);
    int v0 = chunk * K;
    if (v0 >= N) return;
    int vend = v0 + K; if (vend > N) vend = N;
    int g = batch[v0];
    float acc = 0.0f, c = 0.0f;
    for (int v = v0; v < vend; ++v) {
        int gv = batch[v];
        if (gv != g) {
            atomicAdd(&pooled[g * HID + d], acc);
            if (d == 0) atomicAdd(&cnt[g], c);
            acc = 0.0f; c = 0.0f; g = gv;
        }
        acc += bf2f((u32)x[(size_t)v * HID + d]);
        c += 1.0f;
    }
    atomicAdd(&pooled[g * HID + d], acc);
    if (d == 0) atomicAdd(&cnt[g], c);
}

__global__ void k_head(const float* __restrict__ pooled, const float* __restrict__ cnt,
                       const float* __restrict__ Wp, const float* __restrict__ bp,
                       float* __restrict__ out) {
    int g = gtid();
    if (g >= NG) return;
    float inv = 1.0f / fmaxf(cnt[g], 1.0f);
    float l[NC];
#pragma unroll
    for (int c = 0; c < NC; ++c) l[c] = bp[c];
    for (int d = 0; d < HID; ++d) {
        float pv = pooled[g * HID + d] * inv;
#pragma unroll
        for (int c = 0; c < NC; ++c) l[c] = fmaf(pv, Wp[d * NC + c], l[c]);
    }
    float m = l[0];
#pragma unroll
    for (int c = 1; c < NC; ++c) m = fmaxf(m, l[c]);
    float s = 0.0f;
#pragma unroll
    for (int c = 0; c < NC; ++c) s += expf(l[c] - m);
    float ls = logf(s) + m;
#pragma unroll
    for (int c = 0; c < NC; ++c) out[g * NC + c] = l[c] - ls;
}

extern "C" void kernel_launch(void* const* d_in, const int* in_sizes, int n_in,
                              void* d_out, int out_size, void* d_ws, size_t ws_size,
                              hipStream_t stream) {
    const int* ei    = (const int*)d_in[0];
    int E            = in_sizes[0] / 2;
    const int* src   = ei;
    const int* dstp  = ei + E;
    const int* batch = (const int*)d_in[1];
    int N            = in_sizes[1];
    const float* W0  = (const float*)d_in[2];
    const float* b0  = (const float*)d_in[3];
    const float* W1  = (const float*)d_in[4];
    const float* b1  = (const float*)d_in[5];
    const float* W2  = (const float*)d_in[6];
    const float* b2  = (const float*)d_in[7];
    const float* Wp  = (const float*)d_in[8];
    const float* bp  = (const float*)d_in[9];
    float* out       = (float*)d_out;

    // workspace layout
    u16*  xA     = (u16*)d_ws;                    // N*HID bf16
    u16*  xB     = xA + (size_t)N * HID;          // N*HID bf16
    u32*  packed = (u32*)(xB + (size_t)N * HID);  // E u32 (src per CSR slot)
    uint2* tmp   = (uint2*)(packed + E);          // E uint2 (bucket-partitioned {src,dst})
    u16*  Wt1    = (u16*)(tmp + E);               // 128*128 bf16
    u16*  Wt2    = Wt1 + HID * HID;               // 128*128 bf16
    int*  rowptr = (int*)(Wt2 + HID * HID);       // N+1
    int*  bcnt   = rowptr + N + 1;                // 256
    int*  bbase  = bcnt + 256;                    // 257
    int*  bcur   = bbase + 257;                   // 256
    float* dinv  = (float*)(bcur + 256);          // N
    float* pooled= dinv + N;                      // NG*HID
    float* cntg  = pooled + NG * HID;             // NG

    auto cdiv = [](int a, int b) { return (a + b - 1) / b; };
    int NB = cdiv(N, BSZ);                        // 196 buckets

    hipMemsetAsync(bcnt, 0, 256 * sizeof(int), stream);
    hipMemsetAsync(pooled, 0, (NG * HID + NG) * sizeof(float), stream);

    // CSR build (bucket hist -> scan -> partition -> per-bucket sort w/ fused rowptr+dinv)
    k_bhist<<<cdiv(E, TILE), 256, 0, stream>>>(dstp, bcnt, E, NB);
    k_bscan<<<1, 256, 0, stream>>>(bcnt, bbase, bcur, NB, E);
    k_part1<<<cdiv(E, TILE), 256, 0, stream>>>(src, dstp, bcur, tmp, E, NB);
    k_part2<<<NB, 512, 0, stream>>>(bbase, tmp, packed, rowptr, dinv, N, NB);

    // weight prep (bf16, transposed, swizzled)
    k_wt<<<8, 256, 0, stream>>>(W1, Wt1);
    k_wt<<<8, 256, 0, stream>>>(W2, Wt2);

    // layer 0 (rank-1 shortcut)
    k_sl0<<<cdiv(N, 8), 256, 0, stream>>>(rowptr, packed, dinv, W0, b0, xA, N);

    // layer 1: q = dinv*(xA@W1); xA = relu(dinv*(q[v]+sum q[src]) + b1)
    k_gemm<<<cdiv(N, 64), 256, 0, stream>>>(xA, Wt1, dinv, xB, N);
    k_aggr<<<cdiv(N, 8), 256, 0, stream>>>(packed, rowptr, xB, dinv, b1, xA, N);

    // layer 2
    k_gemm<<<cdiv(N, 64), 256, 0, stream>>>(xA, Wt2, dinv, xB, N);
    k_aggr<<<cdiv(N, 8), 256, 0, stream>>>(packed, rowptr, xB, dinv, b2, xA, N);

    // pooling + head
    k_pool<<<cdiv(cdiv(N, 32), 2), 256, 0, stream>>>(xA, batch, pooled, cntg, N);
    k_head<<<2, 256, 0, stream>>>(pooled, cntg, Wp, bp, out);
}